// Round 9
// baseline (69.578 us; speedup 1.0000x reference)
//
#include <hip/hip_runtime.h>

// Problem constants (match reference)
constexpr int cB = 8;
constexpr int cN = 4096;
constexpr int cD = 1024;   // IN_FEATURES
constexpr int cH = 1792;   // HIDDEN_DIM

// Workspace layout (floats)
constexpr size_t OFF_XSUM  = 0;                            // 8192
constexpr size_t OFF_KSUM  = OFF_XSUM + 8192;              // 14336
constexpr size_t OFF_V     = OFF_KSUM + 14336;             // 8192 (fallback path only)
constexpr size_t OFF_C     = OFF_V + 8192;                 // 64   (fallback path only)
constexpr size_t OFF_CPART = OFF_C + 64;                   // 128 (pad 192)
constexpr size_t OFF_VP3   = OFF_CPART + 192;              // 16*8*1024 = 131072
constexpr size_t OFF_PART  = OFF_VP3 + 131072;             // 1024*1024
constexpr size_t TOTAL_DET_FLOATS = OFF_PART + 1048576;    // ~1.21M floats (~4.8 MB)
constexpr size_t SMALL_FLOATS     = OFF_CPART;             // fallback zero region

__device__ __forceinline__ float dot4(float4 a, float4 b) {
    return a.x * b.x + a.y * b.y + a.z * b.z + a.w * b.w;
}

// ---------------------------------------------------------------------------
// k1a (proven): part[b*128+ns][d] = sum of 32 rows of x[b].  x pass 1 (HBM).
__global__ __launch_bounds__(256) void k1a_partial(const float* __restrict__ x,
                                                   float* __restrict__ part) {
    int bid = blockIdx.x;                 // 0..1023
    int b = bid >> 7, ns = bid & 127;
    const float4* xp = (const float4*)(x + ((size_t)b * cN + (size_t)ns * 32) * cD);
    int t = threadIdx.x;
    float4 acc = make_float4(0.f, 0.f, 0.f, 0.f);
#pragma unroll 8
    for (int r = 0; r < 32; ++r) {
        float4 v = xp[(size_t)r * (cD / 4) + t];
        acc.x += v.x; acc.y += v.y; acc.z += v.z; acc.w += v.w;
    }
    ((float4*)part)[(size_t)bid * (cD / 4) + t] = acc;
}

// k1bF: ONE kernel part->xsum. 32 blocks (b,slab) x 512 thr.
// Wave w reduces rows w*16..+15 of its 64-f4-wide slab: lanes read 64
// CONSECUTIVE f4 (1 KB contiguous per load instr) -> full sectors, 16 loads
// in flight per lane; LDS folds the 8 waves.
__global__ __launch_bounds__(512) void k1bF(const float* __restrict__ part,
                                            float* __restrict__ xsum) {
    __shared__ float4 red[8][64];
    int b = blockIdx.x >> 2, slab = blockIdx.x & 3;
    int w = threadIdx.x >> 6, l = threadIdx.x & 63;
    const float4* p = (const float4*)part + ((size_t)b * 128 + w * 16) * 256 + slab * 64 + l;
    float4 acc = make_float4(0.f, 0.f, 0.f, 0.f);
#pragma unroll
    for (int k = 0; k < 16; ++k) {
        float4 u = p[(size_t)k * 256];
        acc.x += u.x; acc.y += u.y; acc.z += u.z; acc.w += u.w;
    }
    red[w][l] = acc;
    __syncthreads();
    if (w == 0) {
        float4 s = make_float4(0.f, 0.f, 0.f, 0.f);
#pragma unroll
        for (int ww = 0; ww < 8; ++ww) {
            float4 u = red[ww][l];
            s.x += u.x; s.y += u.y; s.z += u.z; s.w += u.w;
        }
        ((float4*)xsum)[(size_t)b * 256 + slab * 64 + l] = s;
    }
}

// ---------------------------------------------------------------------------
// KS (proven): ksum[b][h] = xsum[b]·Wk[h] + N*bk[h].  224 blocks x 512.
__global__ __launch_bounds__(512) void KS(const float* __restrict__ xsum,
                                          const float* __restrict__ Wk,
                                          const float* __restrict__ bk,
                                          float* __restrict__ ksum) {
    int w = threadIdx.x >> 6, l = threadIdx.x & 63;
    int b = w;
    int h0 = blockIdx.x * 8;
    const float4* xs4 = (const float4*)(xsum + (size_t)b * cD);
    float4 xr[4];
#pragma unroll
    for (int j = 0; j < 4; ++j) xr[j] = xs4[l + 64 * j];
    for (int i = 0; i < 8; i += 2) {
        int ha = h0 + i, hb = h0 + i + 1;
        const float4* wka = (const float4*)(Wk + (size_t)ha * cD);
        const float4* wkb = (const float4*)(Wk + (size_t)hb * cD);
        float pa = 0.f, pb = 0.f;
#pragma unroll
        for (int j = 0; j < 4; ++j) {
            pa += dot4(wka[l + 64 * j], xr[j]);
            pb += dot4(wkb[l + 64 * j], xr[j]);
        }
#pragma unroll
        for (int off = 32; off; off >>= 1) {
            pa += __shfl_xor(pa, off);
            pb += __shfl_xor(pb, off);
        }
        if (l == 0) {
            ksum[(size_t)b * cH + ha] = pa + (float)cN * bk[ha];
            ksum[(size_t)b * cH + hb] = pb + (float)cN * bk[hb];
        }
    }
}

// ---------------------------------------------------------------------------
// KV (r8-proven + cpart): vpart3[hc][b][d] over disjoint (112h x 64d) Wq tiles.
// dc==0 blocks additionally emit cpart[hc][b] = sum_hh bq[h]*ksum[b][h].
__global__ __launch_bounds__(512) void KV(const float* __restrict__ ksum,
                                          const float* __restrict__ Wq,
                                          const float* __restrict__ bq,
                                          float* __restrict__ vpart3,
                                          float* __restrict__ cpart) {
    __shared__ float ks_l[cB][112];
    __shared__ float red[8][cB][64];
    int hc = blockIdx.x >> 4;             // 0..15 (112 h each)
    int dc = blockIdx.x & 15;             // 0..15 (64 d each)
    int t = threadIdx.x;
    for (int i = t; i < cB * 112; i += 512) {
        int b = i / 112, hh = i % 112;
        ks_l[b][hh] = ksum[(size_t)b * cH + hc * 112 + hh];
    }
    __syncthreads();
    int w = t >> 6, l = t & 63;
    if (dc == 0) {                        // c partial: wave w = batch
        float ca = 0.f;
        if (l < 112)      ca  = bq[hc * 112 + l] * ks_l[w][l];
        if (l + 64 < 112) ca += bq[hc * 112 + l + 64] * ks_l[w][l + 64];
#pragma unroll
        for (int off = 32; off; off >>= 1) ca += __shfl_xor(ca, off);
        if (l == 0) cpart[hc * 8 + w] = ca;
    }
    int d = dc * 64 + l;
    float vacc[cB];
#pragma unroll
    for (int b = 0; b < cB; ++b) vacc[b] = 0.f;
#pragma unroll 2
    for (int i = 0; i < 14; ++i) {
        int hh = w * 14 + i;
        int h = hc * 112 + hh;
        float wv = Wq[(size_t)h * cD + d];
#pragma unroll
        for (int b = 0; b < cB; ++b) vacc[b] = fmaf(ks_l[b][hh], wv, vacc[b]);
    }
#pragma unroll
    for (int b = 0; b < cB; ++b) red[w][b][l] = vacc[b];
    __syncthreads();
    int b = t >> 6, d2 = t & 63;
    float acc = 0.f;
#pragma unroll
    for (int ww = 0; ww < 8; ++ww) acc += red[ww][b][d2];
    vpart3[((size_t)hc * cB + b) * cD + dc * 64 + d2] = acc;
}

// ---------------------------------------------------------------------------
// K4★: folds the vpart3->v reduce (16 f4 loads/thread, L2-hot 512 KB) and the
// cpart->c fold, then 4-row-interleaved score dots.  x pass 2 (L3-warm).
__global__ __launch_bounds__(256) void k4_star(const float* __restrict__ x,
                                               const float* __restrict__ vpart3,
                                               const float* __restrict__ cpart,
                                               float* __restrict__ out) {
    int row0 = blockIdx.x * 16;
    int b = row0 >> 12;                   // row0 / cN
    __shared__ float4 vs[cD / 4];
    __shared__ float cbs;
    int t = threadIdx.x;
    {   // v[b][t-f4] = sum over 16 h-chunks (identical order in every block)
        const float4* vp = (const float4*)vpart3 + (size_t)b * 256 + t;
        float4 a = make_float4(0.f, 0.f, 0.f, 0.f);
#pragma unroll
        for (int hc = 0; hc < 16; ++hc) {
            float4 u = vp[(size_t)hc * 2048];
            a.x += u.x; a.y += u.y; a.z += u.z; a.w += u.w;
        }
        vs[t] = a;
    }
    if (t < 16) {                         // c[b] = sum of 16 cpart chunks
        float ca = cpart[t * 8 + b];
#pragma unroll
        for (int off = 8; off; off >>= 1) ca += __shfl_xor(ca, off);
        if (t == 0) cbs = ca;
    }
    __syncthreads();
    int w = t >> 6, l = t & 63;
    float4 vv[4];
#pragma unroll
    for (int j = 0; j < 4; ++j) vv[j] = vs[l + 64 * j];
    float cb = cbs;
    const float scale = (1.0f / 4096.0f) * (1.0f / sqrtf(1792.0f));
    int row = row0 + w * 4;
    const float4* x0 = (const float4*)(x + (size_t)(row + 0) * cD);
    const float4* x1 = (const float4*)(x + (size_t)(row + 1) * cD);
    const float4* x2 = (const float4*)(x + (size_t)(row + 2) * cD);
    const float4* x3 = (const float4*)(x + (size_t)(row + 3) * cD);
    float a0 = 0.f, a1 = 0.f, a2 = 0.f, a3 = 0.f;
#pragma unroll
    for (int j = 0; j < 4; ++j) {
        a0 += dot4(x0[l + 64 * j], vv[j]);
        a1 += dot4(x1[l + 64 * j], vv[j]);
        a2 += dot4(x2[l + 64 * j], vv[j]);
        a3 += dot4(x3[l + 64 * j], vv[j]);
    }
#pragma unroll
    for (int off = 32; off; off >>= 1) {
        a0 += __shfl_xor(a0, off);
        a1 += __shfl_xor(a1, off);
        a2 += __shfl_xor(a2, off);
        a3 += __shfl_xor(a3, off);
    }
    if (l == 0) {
        out[row + 0] = (a0 + cb) * scale;
        out[row + 1] = (a1 + cb) * scale;
        out[row + 2] = (a2 + cb) * scale;
        out[row + 3] = (a3 + cb) * scale;
    }
}

// ---------------------------------------------------------------------------
// Fallback kernels (ws too small): float atomics, pre-zeroed accumulators.
__global__ __launch_bounds__(256) void k1_atomic(const float* __restrict__ x,
                                                 float* __restrict__ xsum) {
    int bid = blockIdx.x;
    int b = bid >> 7, ns = bid & 127;
    const float4* xp = (const float4*)(x + ((size_t)b * cN + (size_t)ns * 32) * cD);
    int t = threadIdx.x;
    float4 acc = make_float4(0.f, 0.f, 0.f, 0.f);
    for (int r = 0; r < 32; ++r) {
        float4 v = xp[(size_t)r * (cD / 4) + t];
        acc.x += v.x; acc.y += v.y; acc.z += v.z; acc.w += v.w;
    }
    float* dst = xsum + (size_t)b * cD + t * 4;
    atomicAdd(dst + 0, acc.x);
    atomicAdd(dst + 1, acc.y);
    atomicAdd(dst + 2, acc.z);
    atomicAdd(dst + 3, acc.w);
}

__global__ __launch_bounds__(512) void k23_atomic(const float* __restrict__ xsum,
                                                  const float* __restrict__ Wk,
                                                  const float* __restrict__ bk,
                                                  const float* __restrict__ Wq,
                                                  const float* __restrict__ bq,
                                                  float* __restrict__ v,
                                                  float* __restrict__ cvec) {
    int w = threadIdx.x >> 6, l = threadIdx.x & 63;
    int b = w;
    int h0 = blockIdx.x * 8;
    const float4* xs4 = (const float4*)(xsum + (size_t)b * cD);
    float4 xr[4];
#pragma unroll
    for (int j = 0; j < 4; ++j) xr[j] = xs4[l + 64 * j];
    float4 vacc[4];
#pragma unroll
    for (int j = 0; j < 4; ++j) vacc[j] = make_float4(0.f, 0.f, 0.f, 0.f);
    float cacc = 0.f;
    for (int i = 0; i < 8; ++i) {
        int h = h0 + i;
        const float4* wk4 = (const float4*)(Wk + (size_t)h * cD);
        float pd = 0.f;
#pragma unroll
        for (int j = 0; j < 4; ++j) pd += dot4(wk4[l + 64 * j], xr[j]);
#pragma unroll
        for (int off = 32; off; off >>= 1) pd += __shfl_xor(pd, off);
        float ks = pd + (float)cN * bk[h];
        cacc += bq[h] * ks;
        const float4* wq4 = (const float4*)(Wq + (size_t)h * cD);
#pragma unroll
        for (int j = 0; j < 4; ++j) {
            float4 q = wq4[l + 64 * j];
            vacc[j].x = fmaf(q.x, ks, vacc[j].x);
            vacc[j].y = fmaf(q.y, ks, vacc[j].y);
            vacc[j].z = fmaf(q.z, ks, vacc[j].z);
            vacc[j].w = fmaf(q.w, ks, vacc[j].w);
        }
    }
    float* vb = v + (size_t)b * cD;
#pragma unroll
    for (int j = 0; j < 4; ++j) {
        int d = 4 * (l + 64 * j);
        atomicAdd(vb + d + 0, vacc[j].x);
        atomicAdd(vb + d + 1, vacc[j].y);
        atomicAdd(vb + d + 2, vacc[j].z);
        atomicAdd(vb + d + 3, vacc[j].w);
    }
    if (l == 0) atomicAdd(&cvec[b], cacc);
}

__global__ __launch_bounds__(256) void k4_scores(const float* __restrict__ x,
                                                 const float* __restrict__ v,
                                                 const float* __restrict__ cvec,
                                                 float* __restrict__ out) {
    int row0 = blockIdx.x * 16;
    int b = row0 / cN;
    __shared__ float4 vs[cD / 4];
    int t = threadIdx.x;
    vs[t] = ((const float4*)(v + (size_t)b * cD))[t];
    __syncthreads();
    int w = t >> 6, l = t & 63;
    float4 vv[4];
#pragma unroll
    for (int j = 0; j < 4; ++j) vv[j] = vs[l + 64 * j];
    float cb = cvec[b];
    const float scale = (1.0f / 4096.0f) * (1.0f / sqrtf(1792.0f));
    int row = row0 + w * 4;
#pragma unroll
    for (int rp = 0; rp < 2; ++rp) {
        const float4* xa = (const float4*)(x + (size_t)(row + 2 * rp) * cD);
        const float4* xb = (const float4*)(x + (size_t)(row + 2 * rp + 1) * cD);
        float a0 = 0.f, a1 = 0.f;
#pragma unroll
        for (int j = 0; j < 4; ++j) {
            a0 += dot4(xa[l + 64 * j], vv[j]);
            a1 += dot4(xb[l + 64 * j], vv[j]);
        }
#pragma unroll
        for (int off = 32; off; off >>= 1) {
            a0 += __shfl_xor(a0, off);
            a1 += __shfl_xor(a1, off);
        }
        if (l == 0) {
            out[row + 2 * rp]     = (a0 + cb) * scale;
            out[row + 2 * rp + 1] = (a1 + cb) * scale;
        }
    }
}

// ---------------------------------------------------------------------------
extern "C" void kernel_launch(void* const* d_in, const int* in_sizes, int n_in,
                              void* d_out, int out_size, void* d_ws, size_t ws_size,
                              hipStream_t stream) {
    const float* x  = (const float*)d_in[0];
    const float* Wq = (const float*)d_in[1];
    const float* bq = (const float*)d_in[2];
    const float* Wk = (const float*)d_in[3];
    const float* bk = (const float*)d_in[4];
    float* out = (float*)d_out;
    float* ws  = (float*)d_ws;

    float* xsum   = ws + OFF_XSUM;
    float* ksum   = ws + OFF_KSUM;
    float* v      = ws + OFF_V;
    float* cvec   = ws + OFF_C;
    float* cpart  = ws + OFF_CPART;
    float* vpart3 = ws + OFF_VP3;
    float* part   = ws + OFF_PART;

    const bool det = ws_size >= TOTAL_DET_FLOATS * sizeof(float);

    if (det) {
        k1a_partial<<<1024, 256, 0, stream>>>(x, part);            // x pass 1 (HBM, ~20us)
        k1bF<<<32, 512, 0, stream>>>(part, xsum);                  // one-shot part reduce
        KS<<<cH / 8, 512, 0, stream>>>(xsum, Wk, bk, ksum);        // Wk once
        KV<<<256, 512, 0, stream>>>(ksum, Wq, bq, vpart3, cpart);  // Wq once + cpart
        k4_star<<<(cB * cN) / 16, 256, 0, stream>>>(x, vpart3, cpart, out); // fold + pass 2
    } else {
        hipMemsetAsync(d_ws, 0, SMALL_FLOATS * sizeof(float), stream);
        k1_atomic<<<1024, 256, 0, stream>>>(x, xsum);
        k23_atomic<<<cH / 8, 512, 0, stream>>>(xsum, Wk, bk, Wq, bq, v, cvec);
        k4_scores<<<(cB * cN) / 16, 256, 0, stream>>>(x, v, cvec, out);
    }
}